// Round 23
// baseline (56.118 us; speedup 1.0000x reference)
//
#include <hip/hip_runtime.h>
#include <hip/hip_bf16.h>

// B=8192, S=200, E=8, H1=64, H2=32
// att_in = [q, h, q-h, q*h] (32) -> relu(@W1[32,64]+b1) -> relu(@W2[64,32]+b2)
// score = @W3[32,1]+b3 ; mask s<len ; out[b,:] = sum_s score*hist[b,s,:]
//
// R22 champion (Veff K-augmentation, pi-permuted 32x32x16 MFMA, dual-row ILP,
// perm-trick packs, fused prep) + MASK-SPARSITY SKIP: positions s >= len
// contribute exactly 0, so per-row trip count is ceil(len/32) (E ~ 3.6 of 7).
// len is wave-uniform -> scalar branches; loop stays fully unrolled (static
// register indices). Same inputs -> same work (deterministic).
#define BB 8192
#define SS 200

typedef __attribute__((ext_vector_type(8)))  short  short8;
typedef __attribute__((ext_vector_type(4)))  float  f32x4;
typedef __attribute__((ext_vector_type(16))) float  f32x16;

// fast pack: low = bf16(a), high = bf16(b); round-half-up (3 VALU)
__device__ __forceinline__ unsigned int packbf2(float a, float b) {
    union { float f; unsigned int u; } ua, ub;
    ua.f = a; ub.f = b;
    return __builtin_amdgcn_perm(ub.u + 0x8000u, ua.u + 0x8000u, 0x07060302u);
}

// ---- single kernel: 4 waves/block; wave owns TWO adjacent rows ----
__global__ __launch_bounds__(256)
void din16_kernel(const float* __restrict__ query,      // [B,1,8]
                  const float* __restrict__ hist,       // [B,200,8]
                  const int* __restrict__ hlen,         // [B]
                  const float* __restrict__ W1,         // [32,64]
                  const float* __restrict__ b1,         // [64]
                  const float* __restrict__ W2,         // [64,32]
                  const float* __restrict__ b2,         // [32]
                  const float* __restrict__ W3,         // [32]
                  const float* __restrict__ b3,         // [1]
                  float* __restrict__ out)              // [B,1,8]
{
    const int tid  = threadIdx.x;
    const int wave = tid >> 6;
    const int l    = tid & 63;
    const int col  = l & 31;
    const int hi   = l >> 5;
    const int wid  = blockIdx.x * 4 + wave;     // 0..4095
    const int brow0 = 2 * wid, brow1 = 2 * wid + 1;

    const int len0 = hlen[brow0], len1 = hlen[brow1];
    const int nit0 = (len0 + 31) >> 5;          // useful subtiles, 0..7
    const int nit1 = (len1 + 31) >> 5;

    float q0[8], q1[8];
    {
        const float4* p = reinterpret_cast<const float4*>(query + (size_t)brow0 * 8);
        float4 a = p[0], b = p[1];
        q0[0]=a.x; q0[1]=a.y; q0[2]=a.z; q0[3]=a.w; q0[4]=b.x; q0[5]=b.y; q0[6]=b.z; q0[7]=b.w;
    }
    {
        const float4* p = reinterpret_cast<const float4*>(query + (size_t)brow1 * 8);
        float4 a = p[0], b = p[1];
        q1[0]=a.x; q1[1]=a.y; q1[2]=a.z; q1[3]=a.w; q1[4]=b.x; q1[5]=b.y; q1[6]=b.z; q1[7]=b.w;
    }

    // pi(32t + col): col bits [b1 b0|h|r1 r0] -> ibase = 16*b1 + 8*h + 4*b0 + r
    const int cb = (col >> 3) & 3, chh = (col >> 2) & 1, cr = col & 3;
    const int ibase = 16 * (cb >> 1) + 8 * chh + 4 * (cb & 1) + cr;

    // stage-1 A-frags per row, gathered from W1 + q-folded:
    //   hi=0: frag[j] = bf16( (W1[8+j][i]-W1[16+j][i]) + q[j]*W1[24+j][i] )
    //   hi=1: frag[j] = bf16(  W1[j][i]+W1[16+j][i] )            (PB=0)
    short8 a1fA[2], a1fB[2];
#pragma unroll
    for (int t = 0; t < 2; ++t) {
        const int i_ = 32 * t + ibase;
        union { unsigned u[4]; short8 s; } ua, ub;
#pragma unroll
        for (int m = 0; m < 4; ++m) {
            const int j0 = 2 * m, j1 = 2 * m + 1;
            float r1a = W1[(hi ? j0 : 8 + j0) * 64 + i_];
            float r2a = W1[(16 + j0) * 64 + i_];
            float pa0 = hi ? (r1a + r2a) : (r1a - r2a);
            float pb0 = hi ? 0.0f : W1[(24 + j0) * 64 + i_];
            float r1b = W1[(hi ? j1 : 8 + j1) * 64 + i_];
            float r2b = W1[(16 + j1) * 64 + i_];
            float pa1 = hi ? (r1b + r2b) : (r1b - r2b);
            float pb1 = hi ? 0.0f : W1[(24 + j1) * 64 + i_];
            ua.u[m] = packbf2(fmaf(q0[j0], pb0, pa0), fmaf(q0[j1], pb1, pa1));
            ub.u[m] = packbf2(fmaf(q1[j0], pb0, pa0), fmaf(q1[j1], pb1, pa1));
        }
        a1fA[t] = ua.s; a1fB[t] = ub.s;
    }

    // stage-1 B-frag constant half (q values, slots 8..15) per row
    unsigned uqcA[4] = {packbf2(q0[0], q0[1]), packbf2(q0[2], q0[3]),
                        packbf2(q0[4], q0[5]), packbf2(q0[6], q0[7])};
    unsigned uqcB[4] = {packbf2(q1[0], q1[1]), packbf2(q1[2], q1[3]),
                        packbf2(q1[4], q1[5]), packbf2(q1[6], q1[7])};

    // b1 in pi-permuted D-layout: b1c16[t][4u+i] = b1[32t+16*(u>>1)+8hi+4*(u&1)+i]
    f32x16 b1c16[2];
#pragma unroll
    for (int t = 0; t < 2; ++t)
#pragma unroll
        for (int u = 0; u < 4; ++u) {
            f32x4 v = *reinterpret_cast<const f32x4*>(
                b1 + 32 * t + 16 * (u >> 1) + 8 * hi + 4 * (u & 1));
#pragma unroll
            for (int i = 0; i < 4; ++i) b1c16[t][4 * u + i] = v[i];
        }
    f32x16 b2c16, W3v16;
#pragma unroll
    for (int u = 0; u < 4; ++u) {
        f32x4 vb = *reinterpret_cast<const f32x4*>(b2 + 8 * u + 4 * hi);
        f32x4 vw = *reinterpret_cast<const f32x4*>(W3 + 8 * u + 4 * hi);
#pragma unroll
        for (int i = 0; i < 4; ++i) { b2c16[4 * u + i] = vb[i]; W3v16[4 * u + i] = vw[i]; }
    }
    const float b3s = b3[0];

    // stage-2 A-frags gathered from W2: w2f[m][j] = bf16(W2[16m+8hi+j][col])
    short8 w2f[4];
#pragma unroll
    for (int m = 0; m < 4; ++m) {
        union { unsigned u[4]; short8 s; } uw;
#pragma unroll
        for (int d = 0; d < 4; ++d) {
            float x0 = W2[(16 * m + 8 * hi + 2 * d)     * 32 + col];
            float x1 = W2[(16 * m + 8 * hi + 2 * d + 1) * 32 + col];
            uw.u[d] = packbf2(x0, x1);
        }
        w2f[m] = uw.s;
    }

    const float* hrow0 = hist + (size_t)brow0 * SS * 8;
    const float* hrow1 = hist + (size_t)brow1 * SS * 8;

    float accA[8], accB[8];
#pragma unroll
    for (int e = 0; e < 8; ++e) { accA[e] = 0.0f; accB[e] = 0.0f; }

    float hA[2][8], hB[2][8];   // 2-slot rotation per row (static idx)

    auto loadH = [&](const float* hrow, int x, float* h) {
        int s = 32 * x + col;
        if (32 * x + 31 >= SS) s = min(s, SS - 1);      // folds away except x=6
        const float4* p = reinterpret_cast<const float4*>(hrow + (size_t)s * 8);
        float4 v0 = p[0], v1 = p[1];
        h[0]=v0.x; h[1]=v0.y; h[2]=v0.z; h[3]=v0.w;
        h[4]=v1.x; h[5]=v1.y; h[6]=v1.z; h[7]=v1.w;
    };

    // full per-row chain (S1 -> S2 -> score -> pool); rows are independent
    auto CH = [&](const float* h, const short8* a1f, const unsigned* uqc,
                  float* acc, int len, int x) {
        union u_s8 { unsigned u[4]; short8 s; };
        u_s8 ubf;
        ubf.u[0] = hi ? uqc[0] : packbf2(h[0], h[1]);
        ubf.u[1] = hi ? uqc[1] : packbf2(h[2], h[3]);
        ubf.u[2] = hi ? uqc[2] : packbf2(h[4], h[5]);
        ubf.u[3] = hi ? uqc[3] : packbf2(h[6], h[7]);

        f32x16 a1_0 = __builtin_amdgcn_mfma_f32_32x32x16_bf16(a1f[0], ubf.s, b1c16[0], 0, 0, 0);
        f32x16 a1_1 = __builtin_amdgcn_mfma_f32_32x32x16_bf16(a1f[1], ubf.s, b1c16[1], 0, 0, 0);

        u_s8 bB[4];
#pragma unroll
        for (int m = 0; m < 4; ++m) {
#pragma unroll
            for (int d = 0; d < 4; ++d) {
                int p0 = 8 * (m & 1) + 2 * d;
                float lo, hi2;
                if (m >> 1) { lo = a1_1[p0]; hi2 = a1_1[p0 + 1]; }
                else        { lo = a1_0[p0]; hi2 = a1_0[p0 + 1]; }
                bB[m].u[d] = packbf2(fmaxf(lo, 0.f), fmaxf(hi2, 0.f));
            }
        }

        f32x16 a2 = __builtin_amdgcn_mfma_f32_32x32x16_bf16(w2f[0], bB[0].s, b2c16, 0, 0, 0);
        a2 = __builtin_amdgcn_mfma_f32_32x32x16_bf16(w2f[1], bB[1].s, a2, 0, 0, 0);
        a2 = __builtin_amdgcn_mfma_f32_32x32x16_bf16(w2f[2], bB[2].s, a2, 0, 0, 0);
        a2 = __builtin_amdgcn_mfma_f32_32x32x16_bf16(w2f[3], bB[3].s, a2, 0, 0, 0);

        float s0 = 0.f, s1 = 0.f, s2 = 0.f, s3 = 0.f;
#pragma unroll
        for (int r = 0; r < 4; ++r) {
            s0 = fmaf(fmaxf(a2[r],      0.f), W3v16[r],      s0);
            s1 = fmaf(fmaxf(a2[4 + r],  0.f), W3v16[4 + r],  s1);
            s2 = fmaf(fmaxf(a2[8 + r],  0.f), W3v16[8 + r],  s2);
            s3 = fmaf(fmaxf(a2[12 + r], 0.f), W3v16[12 + r], s3);
        }
        float p = (s0 + s1) + (s2 + s3);
        p += __shfl_xor(p, 32);
        float sc = (32 * x + col < len) ? (p + b3s) : 0.0f;
#pragma unroll
        for (int e = 0; e < 8; ++e) acc[e] = fmaf(sc, h[e], acc[e]);
    };

    // pipeline: load(t+1) | chain r0(t) | chain r1(t), fully unrolled with
    // wave-uniform skip of iterations past each row's useful range.
    if (nit0 > 0) loadH(hrow0, 0, hA[0]);
    if (nit1 > 0) loadH(hrow1, 0, hB[0]);
#pragma unroll
    for (int it = 0; it < 7; ++it) {
        if (it + 1 < 7) {
            if (it + 1 < nit0) loadH(hrow0, it + 1, hA[(it + 1) & 1]);
            if (it + 1 < nit1) loadH(hrow1, it + 1, hB[(it + 1) & 1]);
        }
        if (it < nit0) CH(hA[it & 1], a1fA, uqcA, accA, len0, it);
        if (it < nit1) CH(hB[it & 1], a1fB, uqcB, accB, len1, it);
    }

    // reduce over the 32 position-lanes (hi-copies identical)
#pragma unroll
    for (int m = 1; m < 32; m <<= 1)
#pragma unroll
        for (int e = 0; e < 8; ++e) {
            accA[e] += __shfl_xor(accA[e], m);
            accB[e] += __shfl_xor(accB[e], m);
        }

    if (l == 0) {
        float4* op0 = reinterpret_cast<float4*>(out + (size_t)brow0 * 8);
        op0[0] = make_float4(accA[0], accA[1], accA[2], accA[3]);
        op0[1] = make_float4(accA[4], accA[5], accA[6], accA[7]);
        float4* op1 = reinterpret_cast<float4*>(out + (size_t)brow1 * 8);
        op1[0] = make_float4(accB[0], accB[1], accB[2], accB[3]);
        op1[1] = make_float4(accB[4], accB[5], accB[6], accB[7]);
    }
}

extern "C" void kernel_launch(void* const* d_in, const int* in_sizes, int n_in,
                              void* d_out, int out_size, void* d_ws, size_t ws_size,
                              hipStream_t stream) {
    const float* query = (const float*)d_in[0];
    const float* hist  = (const float*)d_in[1];
    const int*   hlen  = (const int*)d_in[2];
    const float* W1    = (const float*)d_in[3];
    const float* b1    = (const float*)d_in[4];
    const float* W2    = (const float*)d_in[5];
    const float* b2    = (const float*)d_in[6];
    const float* W3    = (const float*)d_in[7];
    const float* b3    = (const float*)d_in[8];
    float*       out   = (float*)d_out;

    din16_kernel<<<BB / 8, 256, 0, stream>>>(query, hist, hlen, W1, b1, W2,
                                             b2, W3, b3, out);
}

// Round 24
// 35.575 us; speedup vs baseline: 1.5775x; 1.5775x over previous
//
#include <hip/hip_runtime.h>
#include <hip/hip_bf16.h>

// B=8192, S=200, E=8, H1=64, H2=32
// att_in = [q, h, q-h, q*h] (32) -> relu(@W1[32,64]+b1) -> relu(@W2[64,32]+b2)
// score = @W3[32,1]+b3 ; mask s<len ; out[b,:] = sum_s score*hist[b,s,:]
//
// R22 champion (Veff K-augmentation, pi-permuted 32x32x16 MFMA, dual-row ILP,
// perm-trick packs, fused prep) + COARSE mask-sparsity: a SINGLE wave-uniform
// branch skips iters 4-6 when both rows have len <= 128 (tiles past
// ceil(len/32) contribute only masked zeros -> exact). R23's per-iteration
// branches (14 of them) cost VGPR 112->136 and halved occupancy; one branch
// at one program point keeps live ranges intact.
#define BB 8192
#define SS 200

typedef __attribute__((ext_vector_type(8)))  short  short8;
typedef __attribute__((ext_vector_type(4)))  float  f32x4;
typedef __attribute__((ext_vector_type(16))) float  f32x16;

// fast pack: low = bf16(a), high = bf16(b); round-half-up (3 VALU)
__device__ __forceinline__ unsigned int packbf2(float a, float b) {
    union { float f; unsigned int u; } ua, ub;
    ua.f = a; ub.f = b;
    return __builtin_amdgcn_perm(ub.u + 0x8000u, ua.u + 0x8000u, 0x07060302u);
}

// ---- single kernel: 4 waves/block; wave owns TWO adjacent rows ----
__global__ __launch_bounds__(256)
void din17_kernel(const float* __restrict__ query,      // [B,1,8]
                  const float* __restrict__ hist,       // [B,200,8]
                  const int* __restrict__ hlen,         // [B]
                  const float* __restrict__ W1,         // [32,64]
                  const float* __restrict__ b1,         // [64]
                  const float* __restrict__ W2,         // [64,32]
                  const float* __restrict__ b2,         // [32]
                  const float* __restrict__ W3,         // [32]
                  const float* __restrict__ b3,         // [1]
                  float* __restrict__ out)              // [B,1,8]
{
    const int tid  = threadIdx.x;
    const int wave = tid >> 6;
    const int l    = tid & 63;
    const int col  = l & 31;
    const int hi   = l >> 5;
    const int wid  = blockIdx.x * 4 + wave;     // 0..4095
    const int brow0 = 2 * wid, brow1 = 2 * wid + 1;

    const int len0 = hlen[brow0], len1 = hlen[brow1];

    float q0[8], q1[8];
    {
        const float4* p = reinterpret_cast<const float4*>(query + (size_t)brow0 * 8);
        float4 a = p[0], b = p[1];
        q0[0]=a.x; q0[1]=a.y; q0[2]=a.z; q0[3]=a.w; q0[4]=b.x; q0[5]=b.y; q0[6]=b.z; q0[7]=b.w;
    }
    {
        const float4* p = reinterpret_cast<const float4*>(query + (size_t)brow1 * 8);
        float4 a = p[0], b = p[1];
        q1[0]=a.x; q1[1]=a.y; q1[2]=a.z; q1[3]=a.w; q1[4]=b.x; q1[5]=b.y; q1[6]=b.z; q1[7]=b.w;
    }

    // pi(32t + col): col bits [b1 b0|h|r1 r0] -> ibase = 16*b1 + 8*h + 4*b0 + r
    const int cb = (col >> 3) & 3, chh = (col >> 2) & 1, cr = col & 3;
    const int ibase = 16 * (cb >> 1) + 8 * chh + 4 * (cb & 1) + cr;

    // stage-1 A-frags per row, gathered from W1 + q-folded:
    //   hi=0: frag[j] = bf16( (W1[8+j][i]-W1[16+j][i]) + q[j]*W1[24+j][i] )
    //   hi=1: frag[j] = bf16(  W1[j][i]+W1[16+j][i] )            (PB=0)
    short8 a1fA[2], a1fB[2];
#pragma unroll
    for (int t = 0; t < 2; ++t) {
        const int i_ = 32 * t + ibase;
        union { unsigned u[4]; short8 s; } ua, ub;
#pragma unroll
        for (int m = 0; m < 4; ++m) {
            const int j0 = 2 * m, j1 = 2 * m + 1;
            float r1a = W1[(hi ? j0 : 8 + j0) * 64 + i_];
            float r2a = W1[(16 + j0) * 64 + i_];
            float pa0 = hi ? (r1a + r2a) : (r1a - r2a);
            float pb0 = hi ? 0.0f : W1[(24 + j0) * 64 + i_];
            float r1b = W1[(hi ? j1 : 8 + j1) * 64 + i_];
            float r2b = W1[(16 + j1) * 64 + i_];
            float pa1 = hi ? (r1b + r2b) : (r1b - r2b);
            float pb1 = hi ? 0.0f : W1[(24 + j1) * 64 + i_];
            ua.u[m] = packbf2(fmaf(q0[j0], pb0, pa0), fmaf(q0[j1], pb1, pa1));
            ub.u[m] = packbf2(fmaf(q1[j0], pb0, pa0), fmaf(q1[j1], pb1, pa1));
        }
        a1fA[t] = ua.s; a1fB[t] = ub.s;
    }

    // stage-1 B-frag constant half (q values, slots 8..15) per row
    unsigned uqcA[4] = {packbf2(q0[0], q0[1]), packbf2(q0[2], q0[3]),
                        packbf2(q0[4], q0[5]), packbf2(q0[6], q0[7])};
    unsigned uqcB[4] = {packbf2(q1[0], q1[1]), packbf2(q1[2], q1[3]),
                        packbf2(q1[4], q1[5]), packbf2(q1[6], q1[7])};

    // b1 in pi-permuted D-layout: b1c16[t][4u+i] = b1[32t+16*(u>>1)+8hi+4*(u&1)+i]
    f32x16 b1c16[2];
#pragma unroll
    for (int t = 0; t < 2; ++t)
#pragma unroll
        for (int u = 0; u < 4; ++u) {
            f32x4 v = *reinterpret_cast<const f32x4*>(
                b1 + 32 * t + 16 * (u >> 1) + 8 * hi + 4 * (u & 1));
#pragma unroll
            for (int i = 0; i < 4; ++i) b1c16[t][4 * u + i] = v[i];
        }
    f32x16 b2c16, W3v16;
#pragma unroll
    for (int u = 0; u < 4; ++u) {
        f32x4 vb = *reinterpret_cast<const f32x4*>(b2 + 8 * u + 4 * hi);
        f32x4 vw = *reinterpret_cast<const f32x4*>(W3 + 8 * u + 4 * hi);
#pragma unroll
        for (int i = 0; i < 4; ++i) { b2c16[4 * u + i] = vb[i]; W3v16[4 * u + i] = vw[i]; }
    }
    const float b3s = b3[0];

    // stage-2 A-frags gathered from W2: w2f[m][j] = bf16(W2[16m+8hi+j][col])
    short8 w2f[4];
#pragma unroll
    for (int m = 0; m < 4; ++m) {
        union { unsigned u[4]; short8 s; } uw;
#pragma unroll
        for (int d = 0; d < 4; ++d) {
            float x0 = W2[(16 * m + 8 * hi + 2 * d)     * 32 + col];
            float x1 = W2[(16 * m + 8 * hi + 2 * d + 1) * 32 + col];
            uw.u[d] = packbf2(x0, x1);
        }
        w2f[m] = uw.s;
    }

    const float* hrow0 = hist + (size_t)brow0 * SS * 8;
    const float* hrow1 = hist + (size_t)brow1 * SS * 8;

    float accA[8], accB[8];
#pragma unroll
    for (int e = 0; e < 8; ++e) { accA[e] = 0.0f; accB[e] = 0.0f; }

    float hA[2][8], hB[2][8];   // 2-slot rotation per row (static idx)

    auto loadH = [&](const float* hrow, int x, float* h) {
        int s = 32 * x + col;
        if (32 * x + 31 >= SS) s = min(s, SS - 1);      // folds away except x=6
        const float4* p = reinterpret_cast<const float4*>(hrow + (size_t)s * 8);
        float4 v0 = p[0], v1 = p[1];
        h[0]=v0.x; h[1]=v0.y; h[2]=v0.z; h[3]=v0.w;
        h[4]=v1.x; h[5]=v1.y; h[6]=v1.z; h[7]=v1.w;
    };

    // full per-row chain (S1 -> S2 -> score -> pool); rows are independent
    auto CH = [&](const float* h, const short8* a1f, const unsigned* uqc,
                  float* acc, int len, int x) {
        union u_s8 { unsigned u[4]; short8 s; };
        u_s8 ubf;
        ubf.u[0] = hi ? uqc[0] : packbf2(h[0], h[1]);
        ubf.u[1] = hi ? uqc[1] : packbf2(h[2], h[3]);
        ubf.u[2] = hi ? uqc[2] : packbf2(h[4], h[5]);
        ubf.u[3] = hi ? uqc[3] : packbf2(h[6], h[7]);

        f32x16 a1_0 = __builtin_amdgcn_mfma_f32_32x32x16_bf16(a1f[0], ubf.s, b1c16[0], 0, 0, 0);
        f32x16 a1_1 = __builtin_amdgcn_mfma_f32_32x32x16_bf16(a1f[1], ubf.s, b1c16[1], 0, 0, 0);

        u_s8 bB[4];
#pragma unroll
        for (int m = 0; m < 4; ++m) {
#pragma unroll
            for (int d = 0; d < 4; ++d) {
                int p0 = 8 * (m & 1) + 2 * d;
                float lo, hi2;
                if (m >> 1) { lo = a1_1[p0]; hi2 = a1_1[p0 + 1]; }
                else        { lo = a1_0[p0]; hi2 = a1_0[p0 + 1]; }
                bB[m].u[d] = packbf2(fmaxf(lo, 0.f), fmaxf(hi2, 0.f));
            }
        }

        f32x16 a2 = __builtin_amdgcn_mfma_f32_32x32x16_bf16(w2f[0], bB[0].s, b2c16, 0, 0, 0);
        a2 = __builtin_amdgcn_mfma_f32_32x32x16_bf16(w2f[1], bB[1].s, a2, 0, 0, 0);
        a2 = __builtin_amdgcn_mfma_f32_32x32x16_bf16(w2f[2], bB[2].s, a2, 0, 0, 0);
        a2 = __builtin_amdgcn_mfma_f32_32x32x16_bf16(w2f[3], bB[3].s, a2, 0, 0, 0);

        float s0 = 0.f, s1 = 0.f, s2 = 0.f, s3 = 0.f;
#pragma unroll
        for (int r = 0; r < 4; ++r) {
            s0 = fmaf(fmaxf(a2[r],      0.f), W3v16[r],      s0);
            s1 = fmaf(fmaxf(a2[4 + r],  0.f), W3v16[4 + r],  s1);
            s2 = fmaf(fmaxf(a2[8 + r],  0.f), W3v16[8 + r],  s2);
            s3 = fmaf(fmaxf(a2[12 + r], 0.f), W3v16[12 + r], s3);
        }
        float p = (s0 + s1) + (s2 + s3);
        p += __shfl_xor(p, 32);
        float sc = (32 * x + col < len) ? (p + b3s) : 0.0f;
#pragma unroll
        for (int e = 0; e < 8; ++e) acc[e] = fmaf(sc, h[e], acc[e]);
    };

    // ---- pipeline: unconditional iters 0..3, ONE guarded suffix 4..6 ----
    loadH(hrow0, 0, hA[0]);
    loadH(hrow1, 0, hB[0]);
#pragma unroll
    for (int it = 0; it < 4; ++it) {
        loadH(hrow0, it + 1, hA[(it + 1) & 1]);   // it+1 <= 4
        loadH(hrow1, it + 1, hB[(it + 1) & 1]);
        CH(hA[it & 1], a1fA, uqcA, accA, len0, it);
        CH(hB[it & 1], a1fB, uqcB, accB, len1, it);
    }
    // tiles 4..6 only matter when some row has len > 128 (else masked zeros)
    if (len0 > 128 || len1 > 128) {
#pragma unroll
        for (int it = 4; it < 7; ++it) {
            if (it + 1 < 7) {
                loadH(hrow0, it + 1, hA[(it + 1) & 1]);
                loadH(hrow1, it + 1, hB[(it + 1) & 1]);
            }
            CH(hA[it & 1], a1fA, uqcA, accA, len0, it);
            CH(hB[it & 1], a1fB, uqcB, accB, len1, it);
        }
    }

    // reduce over the 32 position-lanes (hi-copies identical)
#pragma unroll
    for (int m = 1; m < 32; m <<= 1)
#pragma unroll
        for (int e = 0; e < 8; ++e) {
            accA[e] += __shfl_xor(accA[e], m);
            accB[e] += __shfl_xor(accB[e], m);
        }

    if (l == 0) {
        float4* op0 = reinterpret_cast<float4*>(out + (size_t)brow0 * 8);
        op0[0] = make_float4(accA[0], accA[1], accA[2], accA[3]);
        op0[1] = make_float4(accA[4], accA[5], accA[6], accA[7]);
        float4* op1 = reinterpret_cast<float4*>(out + (size_t)brow1 * 8);
        op1[0] = make_float4(accB[0], accB[1], accB[2], accB[3]);
        op1[1] = make_float4(accB[4], accB[5], accB[6], accB[7]);
    }
}

extern "C" void kernel_launch(void* const* d_in, const int* in_sizes, int n_in,
                              void* d_out, int out_size, void* d_ws, size_t ws_size,
                              hipStream_t stream) {
    const float* query = (const float*)d_in[0];
    const float* hist  = (const float*)d_in[1];
    const int*   hlen  = (const int*)d_in[2];
    const float* W1    = (const float*)d_in[3];
    const float* b1    = (const float*)d_in[4];
    const float* W2    = (const float*)d_in[5];
    const float* b2    = (const float*)d_in[6];
    const float* W3    = (const float*)d_in[7];
    const float* b3    = (const float*)d_in[8];
    float*       out   = (float*)d_out;

    din17_kernel<<<BB / 8, 256, 0, stream>>>(query, hist, hlen, W1, b1, W2,
                                             b2, W3, b3, out);
}

// Round 25
// 35.036 us; speedup vs baseline: 1.6017x; 1.0154x over previous
//
#include <hip/hip_runtime.h>
#include <hip/hip_bf16.h>

// B=8192, S=200, E=8, H1=64, H2=32
// att_in = [q, h, q-h, q*h] (32) -> relu(@W1[32,64]+b1) -> relu(@W2[64,32]+b2)
// score = @W3[32,1]+b3 ; mask s<len ; out[b,:] = sum_s score*hist[b,s,:]
//
// R22 champion (Veff K-augmentation, pi-permuted 32x32x16 MFMA, dual-row ILP,
// perm-trick packs, fused prep) with the 7-iter pipeline ROLLED (trip-3 loop,
// body = 2 iterations with explicit even/odd slots, + epilogue): tests the
// I-fetch theory (fully-unrolled ~3000-inst body vs 32KB L1I at 2 waves/SIMD).
#define BB 8192
#define SS 200

typedef __attribute__((ext_vector_type(8)))  short  short8;
typedef __attribute__((ext_vector_type(4)))  float  f32x4;
typedef __attribute__((ext_vector_type(16))) float  f32x16;

// fast pack: low = bf16(a), high = bf16(b); round-half-up (3 VALU)
__device__ __forceinline__ unsigned int packbf2(float a, float b) {
    union { float f; unsigned int u; } ua, ub;
    ua.f = a; ub.f = b;
    return __builtin_amdgcn_perm(ub.u + 0x8000u, ua.u + 0x8000u, 0x07060302u);
}

// ---- single kernel: 4 waves/block; wave owns TWO adjacent rows ----
__global__ __launch_bounds__(256)
void din18_kernel(const float* __restrict__ query,      // [B,1,8]
                  const float* __restrict__ hist,       // [B,200,8]
                  const int* __restrict__ hlen,         // [B]
                  const float* __restrict__ W1,         // [32,64]
                  const float* __restrict__ b1,         // [64]
                  const float* __restrict__ W2,         // [64,32]
                  const float* __restrict__ b2,         // [32]
                  const float* __restrict__ W3,         // [32]
                  const float* __restrict__ b3,         // [1]
                  float* __restrict__ out)              // [B,1,8]
{
    const int tid  = threadIdx.x;
    const int wave = tid >> 6;
    const int l    = tid & 63;
    const int col  = l & 31;
    const int hi   = l >> 5;
    const int wid  = blockIdx.x * 4 + wave;     // 0..4095
    const int brow0 = 2 * wid, brow1 = 2 * wid + 1;

    const int len0 = hlen[brow0], len1 = hlen[brow1];

    float q0[8], q1[8];
    {
        const float4* p = reinterpret_cast<const float4*>(query + (size_t)brow0 * 8);
        float4 a = p[0], b = p[1];
        q0[0]=a.x; q0[1]=a.y; q0[2]=a.z; q0[3]=a.w; q0[4]=b.x; q0[5]=b.y; q0[6]=b.z; q0[7]=b.w;
    }
    {
        const float4* p = reinterpret_cast<const float4*>(query + (size_t)brow1 * 8);
        float4 a = p[0], b = p[1];
        q1[0]=a.x; q1[1]=a.y; q1[2]=a.z; q1[3]=a.w; q1[4]=b.x; q1[5]=b.y; q1[6]=b.z; q1[7]=b.w;
    }

    // pi(32t + col): col bits [b1 b0|h|r1 r0] -> ibase = 16*b1 + 8*h + 4*b0 + r
    const int cb = (col >> 3) & 3, chh = (col >> 2) & 1, cr = col & 3;
    const int ibase = 16 * (cb >> 1) + 8 * chh + 4 * (cb & 1) + cr;

    // stage-1 A-frags per row, gathered from W1 + q-folded:
    //   hi=0: frag[j] = bf16( (W1[8+j][i]-W1[16+j][i]) + q[j]*W1[24+j][i] )
    //   hi=1: frag[j] = bf16(  W1[j][i]+W1[16+j][i] )            (PB=0)
    short8 a1fA[2], a1fB[2];
#pragma unroll
    for (int t = 0; t < 2; ++t) {
        const int i_ = 32 * t + ibase;
        union { unsigned u[4]; short8 s; } ua, ub;
#pragma unroll
        for (int m = 0; m < 4; ++m) {
            const int j0 = 2 * m, j1 = 2 * m + 1;
            float r1a = W1[(hi ? j0 : 8 + j0) * 64 + i_];
            float r2a = W1[(16 + j0) * 64 + i_];
            float pa0 = hi ? (r1a + r2a) : (r1a - r2a);
            float pb0 = hi ? 0.0f : W1[(24 + j0) * 64 + i_];
            float r1b = W1[(hi ? j1 : 8 + j1) * 64 + i_];
            float r2b = W1[(16 + j1) * 64 + i_];
            float pa1 = hi ? (r1b + r2b) : (r1b - r2b);
            float pb1 = hi ? 0.0f : W1[(24 + j1) * 64 + i_];
            ua.u[m] = packbf2(fmaf(q0[j0], pb0, pa0), fmaf(q0[j1], pb1, pa1));
            ub.u[m] = packbf2(fmaf(q1[j0], pb0, pa0), fmaf(q1[j1], pb1, pa1));
        }
        a1fA[t] = ua.s; a1fB[t] = ub.s;
    }

    // stage-1 B-frag constant half (q values, slots 8..15) per row
    unsigned uqcA[4] = {packbf2(q0[0], q0[1]), packbf2(q0[2], q0[3]),
                        packbf2(q0[4], q0[5]), packbf2(q0[6], q0[7])};
    unsigned uqcB[4] = {packbf2(q1[0], q1[1]), packbf2(q1[2], q1[3]),
                        packbf2(q1[4], q1[5]), packbf2(q1[6], q1[7])};

    // b1 in pi-permuted D-layout: b1c16[t][4u+i] = b1[32t+16*(u>>1)+8hi+4*(u&1)+i]
    f32x16 b1c16[2];
#pragma unroll
    for (int t = 0; t < 2; ++t)
#pragma unroll
        for (int u = 0; u < 4; ++u) {
            f32x4 v = *reinterpret_cast<const f32x4*>(
                b1 + 32 * t + 16 * (u >> 1) + 8 * hi + 4 * (u & 1));
#pragma unroll
            for (int i = 0; i < 4; ++i) b1c16[t][4 * u + i] = v[i];
        }
    f32x16 b2c16, W3v16;
#pragma unroll
    for (int u = 0; u < 4; ++u) {
        f32x4 vb = *reinterpret_cast<const f32x4*>(b2 + 8 * u + 4 * hi);
        f32x4 vw = *reinterpret_cast<const f32x4*>(W3 + 8 * u + 4 * hi);
#pragma unroll
        for (int i = 0; i < 4; ++i) { b2c16[4 * u + i] = vb[i]; W3v16[4 * u + i] = vw[i]; }
    }
    const float b3s = b3[0];

    // stage-2 A-frags gathered from W2: w2f[m][j] = bf16(W2[16m+8hi+j][col])
    short8 w2f[4];
#pragma unroll
    for (int m = 0; m < 4; ++m) {
        union { unsigned u[4]; short8 s; } uw;
#pragma unroll
        for (int d = 0; d < 4; ++d) {
            float x0 = W2[(16 * m + 8 * hi + 2 * d)     * 32 + col];
            float x1 = W2[(16 * m + 8 * hi + 2 * d + 1) * 32 + col];
            uw.u[d] = packbf2(x0, x1);
        }
        w2f[m] = uw.s;
    }

    const float* hrow0 = hist + (size_t)brow0 * SS * 8;
    const float* hrow1 = hist + (size_t)brow1 * SS * 8;

    float accA[8], accB[8];
#pragma unroll
    for (int e = 0; e < 8; ++e) { accA[e] = 0.0f; accB[e] = 0.0f; }

    float hA[2][8], hB[2][8];   // explicit even/odd slots (static idx only)

    // runtime-x load: clamp always (folds to the same asm as min once)
    auto loadHd = [&](const float* hrow, int x, float* h) {
        int s = min(32 * x + col, SS - 1);
        const float4* p = reinterpret_cast<const float4*>(hrow + (size_t)s * 8);
        float4 v0 = p[0], v1 = p[1];
        h[0]=v0.x; h[1]=v0.y; h[2]=v0.z; h[3]=v0.w;
        h[4]=v1.x; h[5]=v1.y; h[6]=v1.z; h[7]=v1.w;
    };

    // full per-row chain (S1 -> S2 -> score -> pool); x is runtime
    auto CH = [&](const float* h, const short8* a1f, const unsigned* uqc,
                  float* acc, int len, int x) {
        union u_s8 { unsigned u[4]; short8 s; };
        u_s8 ubf;
        ubf.u[0] = hi ? uqc[0] : packbf2(h[0], h[1]);
        ubf.u[1] = hi ? uqc[1] : packbf2(h[2], h[3]);
        ubf.u[2] = hi ? uqc[2] : packbf2(h[4], h[5]);
        ubf.u[3] = hi ? uqc[3] : packbf2(h[6], h[7]);

        f32x16 a1_0 = __builtin_amdgcn_mfma_f32_32x32x16_bf16(a1f[0], ubf.s, b1c16[0], 0, 0, 0);
        f32x16 a1_1 = __builtin_amdgcn_mfma_f32_32x32x16_bf16(a1f[1], ubf.s, b1c16[1], 0, 0, 0);

        u_s8 bB[4];
#pragma unroll
        for (int m = 0; m < 4; ++m) {
#pragma unroll
            for (int d = 0; d < 4; ++d) {
                int p0 = 8 * (m & 1) + 2 * d;
                float lo, hi2;
                if (m >> 1) { lo = a1_1[p0]; hi2 = a1_1[p0 + 1]; }
                else        { lo = a1_0[p0]; hi2 = a1_0[p0 + 1]; }
                bB[m].u[d] = packbf2(fmaxf(lo, 0.f), fmaxf(hi2, 0.f));
            }
        }

        f32x16 a2 = __builtin_amdgcn_mfma_f32_32x32x16_bf16(w2f[0], bB[0].s, b2c16, 0, 0, 0);
        a2 = __builtin_amdgcn_mfma_f32_32x32x16_bf16(w2f[1], bB[1].s, a2, 0, 0, 0);
        a2 = __builtin_amdgcn_mfma_f32_32x32x16_bf16(w2f[2], bB[2].s, a2, 0, 0, 0);
        a2 = __builtin_amdgcn_mfma_f32_32x32x16_bf16(w2f[3], bB[3].s, a2, 0, 0, 0);

        float s0 = 0.f, s1 = 0.f, s2 = 0.f, s3 = 0.f;
#pragma unroll
        for (int r = 0; r < 4; ++r) {
            s0 = fmaf(fmaxf(a2[r],      0.f), W3v16[r],      s0);
            s1 = fmaf(fmaxf(a2[4 + r],  0.f), W3v16[4 + r],  s1);
            s2 = fmaf(fmaxf(a2[8 + r],  0.f), W3v16[8 + r],  s2);
            s3 = fmaf(fmaxf(a2[12 + r], 0.f), W3v16[12 + r], s3);
        }
        float p = (s0 + s1) + (s2 + s3);
        p += __shfl_xor(p, 32);
        float sc = (32 * x + col < len) ? (p + b3s) : 0.0f;
#pragma unroll
        for (int e = 0; e < 8; ++e) acc[e] = fmaf(sc, h[e], acc[e]);
    };

    // ---- rolled pipeline: trip-3 loop, body = 2 iterations, + epilogue x=6 ----
    loadHd(hrow0, 0, hA[0]);
    loadHd(hrow1, 0, hB[0]);
#pragma unroll 1
    for (int xb = 0; xb < 6; xb += 2) {
        loadHd(hrow0, xb + 1, hA[1]);
        loadHd(hrow1, xb + 1, hB[1]);
        CH(hA[0], a1fA, uqcA, accA, len0, xb);
        CH(hB[0], a1fB, uqcB, accB, len1, xb);
        loadHd(hrow0, xb + 2, hA[0]);   // xb+2 <= 6
        loadHd(hrow1, xb + 2, hB[0]);
        CH(hA[1], a1fA, uqcA, accA, len0, xb + 1);
        CH(hB[1], a1fB, uqcB, accB, len1, xb + 1);
    }
    CH(hA[0], a1fA, uqcA, accA, len0, 6);
    CH(hB[0], a1fB, uqcB, accB, len1, 6);

    // reduce over the 32 position-lanes (hi-copies identical)
#pragma unroll
    for (int m = 1; m < 32; m <<= 1)
#pragma unroll
        for (int e = 0; e < 8; ++e) {
            accA[e] += __shfl_xor(accA[e], m);
            accB[e] += __shfl_xor(accB[e], m);
        }

    if (l == 0) {
        float4* op0 = reinterpret_cast<float4*>(out + (size_t)brow0 * 8);
        op0[0] = make_float4(accA[0], accA[1], accA[2], accA[3]);
        op0[1] = make_float4(accA[4], accA[5], accA[6], accA[7]);
        float4* op1 = reinterpret_cast<float4*>(out + (size_t)brow1 * 8);
        op1[0] = make_float4(accB[0], accB[1], accB[2], accB[3]);
        op1[1] = make_float4(accB[4], accB[5], accB[6], accB[7]);
    }
}

extern "C" void kernel_launch(void* const* d_in, const int* in_sizes, int n_in,
                              void* d_out, int out_size, void* d_ws, size_t ws_size,
                              hipStream_t stream) {
    const float* query = (const float*)d_in[0];
    const float* hist  = (const float*)d_in[1];
    const int*   hlen  = (const int*)d_in[2];
    const float* W1    = (const float*)d_in[3];
    const float* b1    = (const float*)d_in[4];
    const float* W2    = (const float*)d_in[5];
    const float* b2    = (const float*)d_in[6];
    const float* W3    = (const float*)d_in[7];
    const float* b3    = (const float*)d_in[8];
    float*       out   = (float*)d_out;

    din18_kernel<<<BB / 8, 256, 0, stream>>>(query, hist, hlen, W1, b1, W2,
                                             b2, W3, b3, out);
}

// Round 26
// 33.893 us; speedup vs baseline: 1.6557x; 1.0337x over previous
//
#include <hip/hip_runtime.h>
#include <hip/hip_bf16.h>

// B=8192, S=200, E=8, H1=64, H2=32
// att_in = [q, h, q-h, q*h] (32) -> relu(@W1[32,64]+b1) -> relu(@W2[64,32]+b2)
// score = @W3[32,1]+b3 ; mask s<len ; out[b,:] = sum_s score*hist[b,s,:]
//
// FINAL CHAMPION (R22, 33.96us; 6.5x over fp32 baseline):
//  - Veff rank reduction with K-AUGMENTATION (32x32x16 MFMA): h1 = Veff(q).h
//    (k=0..7, hi=0 lanes) + P0.q (k=8..15, hi=1 lanes) + b1 (C-operand).
//  - pi bit-permutation on W1 columns/b1 makes stage-1 MFMA D-layout coincide
//    with stage-2 B-frag layout: zero LDS, zero shuffles between stages.
//  - dual-row per wave (2 independent chains) for ILP at the structural
//    2-waves/SIMD residency cap (unified VGPR+AGPR 129-256 band).
//  - perm-trick bf16 packs (3 VALU; inline-asm cvt_pk pins VGPRs: -23%, R20).
//  - prep fused into the main kernel: ONE dispatch (serialized prep launch
//    cost 4.3us, R22).
//  Falsified levers: sparsity-skip (R23/R24: FETCH drops but codegen/residency
//  regress), rolled loop (R25), deeper prefetch (R9), launch_bounds (R11/R16).
#define BB 8192
#define SS 200

typedef __attribute__((ext_vector_type(8)))  short  short8;
typedef __attribute__((ext_vector_type(4)))  float  f32x4;
typedef __attribute__((ext_vector_type(16))) float  f32x16;

// fast pack: low = bf16(a), high = bf16(b); round-half-up (3 VALU)
__device__ __forceinline__ unsigned int packbf2(float a, float b) {
    union { float f; unsigned int u; } ua, ub;
    ua.f = a; ub.f = b;
    return __builtin_amdgcn_perm(ub.u + 0x8000u, ua.u + 0x8000u, 0x07060302u);
}

// ---- single kernel: 4 waves/block; wave owns TWO adjacent rows; 7 iters ----
__global__ __launch_bounds__(256)
void din15_kernel(const float* __restrict__ query,      // [B,1,8]
                  const float* __restrict__ hist,       // [B,200,8]
                  const int* __restrict__ hlen,         // [B]
                  const float* __restrict__ W1,         // [32,64]
                  const float* __restrict__ b1,         // [64]
                  const float* __restrict__ W2,         // [64,32]
                  const float* __restrict__ b2,         // [32]
                  const float* __restrict__ W3,         // [32]
                  const float* __restrict__ b3,         // [1]
                  float* __restrict__ out)              // [B,1,8]
{
    const int tid  = threadIdx.x;
    const int wave = tid >> 6;
    const int l    = tid & 63;
    const int col  = l & 31;
    const int hi   = l >> 5;
    const int wid  = blockIdx.x * 4 + wave;     // 0..4095
    const int brow0 = 2 * wid, brow1 = 2 * wid + 1;

    const int len0 = hlen[brow0], len1 = hlen[brow1];

    float q0[8], q1[8];
    {
        const float4* p = reinterpret_cast<const float4*>(query + (size_t)brow0 * 8);
        float4 a = p[0], b = p[1];
        q0[0]=a.x; q0[1]=a.y; q0[2]=a.z; q0[3]=a.w; q0[4]=b.x; q0[5]=b.y; q0[6]=b.z; q0[7]=b.w;
    }
    {
        const float4* p = reinterpret_cast<const float4*>(query + (size_t)brow1 * 8);
        float4 a = p[0], b = p[1];
        q1[0]=a.x; q1[1]=a.y; q1[2]=a.z; q1[3]=a.w; q1[4]=b.x; q1[5]=b.y; q1[6]=b.z; q1[7]=b.w;
    }

    // pi(32t + col): col bits [b1 b0|h|r1 r0] -> ibase = 16*b1 + 8*h + 4*b0 + r
    const int cb = (col >> 3) & 3, chh = (col >> 2) & 1, cr = col & 3;
    const int ibase = 16 * (cb >> 1) + 8 * chh + 4 * (cb & 1) + cr;

    // stage-1 A-frags per row, gathered from W1 + q-folded:
    //   hi=0: frag[j] = bf16( (W1[8+j][i]-W1[16+j][i]) + q[j]*W1[24+j][i] )
    //   hi=1: frag[j] = bf16(  W1[j][i]+W1[16+j][i] )            (PB=0)
    short8 a1fA[2], a1fB[2];
#pragma unroll
    for (int t = 0; t < 2; ++t) {
        const int i_ = 32 * t + ibase;
        union { unsigned u[4]; short8 s; } ua, ub;
#pragma unroll
        for (int m = 0; m < 4; ++m) {
            const int j0 = 2 * m, j1 = 2 * m + 1;
            float r1a = W1[(hi ? j0 : 8 + j0) * 64 + i_];
            float r2a = W1[(16 + j0) * 64 + i_];
            float pa0 = hi ? (r1a + r2a) : (r1a - r2a);
            float pb0 = hi ? 0.0f : W1[(24 + j0) * 64 + i_];
            float r1b = W1[(hi ? j1 : 8 + j1) * 64 + i_];
            float r2b = W1[(16 + j1) * 64 + i_];
            float pa1 = hi ? (r1b + r2b) : (r1b - r2b);
            float pb1 = hi ? 0.0f : W1[(24 + j1) * 64 + i_];
            ua.u[m] = packbf2(fmaf(q0[j0], pb0, pa0), fmaf(q0[j1], pb1, pa1));
            ub.u[m] = packbf2(fmaf(q1[j0], pb0, pa0), fmaf(q1[j1], pb1, pa1));
        }
        a1fA[t] = ua.s; a1fB[t] = ub.s;
    }

    // stage-1 B-frag constant half (q values, slots 8..15) per row
    unsigned uqcA[4] = {packbf2(q0[0], q0[1]), packbf2(q0[2], q0[3]),
                        packbf2(q0[4], q0[5]), packbf2(q0[6], q0[7])};
    unsigned uqcB[4] = {packbf2(q1[0], q1[1]), packbf2(q1[2], q1[3]),
                        packbf2(q1[4], q1[5]), packbf2(q1[6], q1[7])};

    // b1 in pi-permuted D-layout: b1c16[t][4u+i] = b1[32t+16*(u>>1)+8hi+4*(u&1)+i]
    f32x16 b1c16[2];
#pragma unroll
    for (int t = 0; t < 2; ++t)
#pragma unroll
        for (int u = 0; u < 4; ++u) {
            f32x4 v = *reinterpret_cast<const f32x4*>(
                b1 + 32 * t + 16 * (u >> 1) + 8 * hi + 4 * (u & 1));
#pragma unroll
            for (int i = 0; i < 4; ++i) b1c16[t][4 * u + i] = v[i];
        }
    f32x16 b2c16, W3v16;
#pragma unroll
    for (int u = 0; u < 4; ++u) {
        f32x4 vb = *reinterpret_cast<const f32x4*>(b2 + 8 * u + 4 * hi);
        f32x4 vw = *reinterpret_cast<const f32x4*>(W3 + 8 * u + 4 * hi);
#pragma unroll
        for (int i = 0; i < 4; ++i) { b2c16[4 * u + i] = vb[i]; W3v16[4 * u + i] = vw[i]; }
    }
    const float b3s = b3[0];

    // stage-2 A-frags gathered from W2: w2f[m][j] = bf16(W2[16m+8hi+j][col])
    short8 w2f[4];
#pragma unroll
    for (int m = 0; m < 4; ++m) {
        union { unsigned u[4]; short8 s; } uw;
#pragma unroll
        for (int d = 0; d < 4; ++d) {
            float x0 = W2[(16 * m + 8 * hi + 2 * d)     * 32 + col];
            float x1 = W2[(16 * m + 8 * hi + 2 * d + 1) * 32 + col];
            uw.u[d] = packbf2(x0, x1);
        }
        w2f[m] = uw.s;
    }

    const float* hrow0 = hist + (size_t)brow0 * SS * 8;
    const float* hrow1 = hist + (size_t)brow1 * SS * 8;

    float accA[8], accB[8];
#pragma unroll
    for (int e = 0; e < 8; ++e) { accA[e] = 0.0f; accB[e] = 0.0f; }

    float hA[2][8], hB[2][8];   // 2-slot rotation per row (static idx)

    auto loadH = [&](const float* hrow, int x, float* h) {
        int s = 32 * x + col;
        if (32 * x + 31 >= SS) s = min(s, SS - 1);      // folds away except x=6
        const float4* p = reinterpret_cast<const float4*>(hrow + (size_t)s * 8);
        float4 v0 = p[0], v1 = p[1];
        h[0]=v0.x; h[1]=v0.y; h[2]=v0.z; h[3]=v0.w;
        h[4]=v1.x; h[5]=v1.y; h[6]=v1.z; h[7]=v1.w;
    };

    // full per-row chain (S1 -> S2 -> score -> pool); rows are independent
    auto CH = [&](const float* h, const short8* a1f, const unsigned* uqc,
                  float* acc, int len, int x) {
        union u_s8 { unsigned u[4]; short8 s; };
        u_s8 ubf;
        ubf.u[0] = hi ? uqc[0] : packbf2(h[0], h[1]);
        ubf.u[1] = hi ? uqc[1] : packbf2(h[2], h[3]);
        ubf.u[2] = hi ? uqc[2] : packbf2(h[4], h[5]);
        ubf.u[3] = hi ? uqc[3] : packbf2(h[6], h[7]);

        f32x16 a1_0 = __builtin_amdgcn_mfma_f32_32x32x16_bf16(a1f[0], ubf.s, b1c16[0], 0, 0, 0);
        f32x16 a1_1 = __builtin_amdgcn_mfma_f32_32x32x16_bf16(a1f[1], ubf.s, b1c16[1], 0, 0, 0);

        u_s8 bB[4];
#pragma unroll
        for (int m = 0; m < 4; ++m) {
#pragma unroll
            for (int d = 0; d < 4; ++d) {
                int p0 = 8 * (m & 1) + 2 * d;
                float lo, hi2;
                if (m >> 1) { lo = a1_1[p0]; hi2 = a1_1[p0 + 1]; }
                else        { lo = a1_0[p0]; hi2 = a1_0[p0 + 1]; }
                bB[m].u[d] = packbf2(fmaxf(lo, 0.f), fmaxf(hi2, 0.f));
            }
        }

        f32x16 a2 = __builtin_amdgcn_mfma_f32_32x32x16_bf16(w2f[0], bB[0].s, b2c16, 0, 0, 0);
        a2 = __builtin_amdgcn_mfma_f32_32x32x16_bf16(w2f[1], bB[1].s, a2, 0, 0, 0);
        a2 = __builtin_amdgcn_mfma_f32_32x32x16_bf16(w2f[2], bB[2].s, a2, 0, 0, 0);
        a2 = __builtin_amdgcn_mfma_f32_32x32x16_bf16(w2f[3], bB[3].s, a2, 0, 0, 0);

        float s0 = 0.f, s1 = 0.f, s2 = 0.f, s3 = 0.f;
#pragma unroll
        for (int r = 0; r < 4; ++r) {
            s0 = fmaf(fmaxf(a2[r],      0.f), W3v16[r],      s0);
            s1 = fmaf(fmaxf(a2[4 + r],  0.f), W3v16[4 + r],  s1);
            s2 = fmaf(fmaxf(a2[8 + r],  0.f), W3v16[8 + r],  s2);
            s3 = fmaf(fmaxf(a2[12 + r], 0.f), W3v16[12 + r], s3);
        }
        float p = (s0 + s1) + (s2 + s3);
        p += __shfl_xor(p, 32);
        float sc = (32 * x + col < len) ? (p + b3s) : 0.0f;
#pragma unroll
        for (int e = 0; e < 8; ++e) acc[e] = fmaf(sc, h[e], acc[e]);
    };

    // pipeline: load(t+1) both rows | chain r0(t) | chain r1(t) — fully unrolled
    loadH(hrow0, 0, hA[0]);
    loadH(hrow1, 0, hB[0]);
#pragma unroll
    for (int it = 0; it < 7; ++it) {
        if (it + 1 < 7) {
            loadH(hrow0, it + 1, hA[(it + 1) & 1]);
            loadH(hrow1, it + 1, hB[(it + 1) & 1]);
        }
        CH(hA[it & 1], a1fA, uqcA, accA, len0, it);
        CH(hB[it & 1], a1fB, uqcB, accB, len1, it);
    }

    // reduce over the 32 position-lanes (hi-copies identical)
#pragma unroll
    for (int m = 1; m < 32; m <<= 1)
#pragma unroll
        for (int e = 0; e < 8; ++e) {
            accA[e] += __shfl_xor(accA[e], m);
            accB[e] += __shfl_xor(accB[e], m);
        }

    if (l == 0) {
        float4* op0 = reinterpret_cast<float4*>(out + (size_t)brow0 * 8);
        op0[0] = make_float4(accA[0], accA[1], accA[2], accA[3]);
        op0[1] = make_float4(accA[4], accA[5], accA[6], accA[7]);
        float4* op1 = reinterpret_cast<float4*>(out + (size_t)brow1 * 8);
        op1[0] = make_float4(accB[0], accB[1], accB[2], accB[3]);
        op1[1] = make_float4(accB[4], accB[5], accB[6], accB[7]);
    }
}

extern "C" void kernel_launch(void* const* d_in, const int* in_sizes, int n_in,
                              void* d_out, int out_size, void* d_ws, size_t ws_size,
                              hipStream_t stream) {
    const float* query = (const float*)d_in[0];
    const float* hist  = (const float*)d_in[1];
    const int*   hlen  = (const int*)d_in[2];
    const float* W1    = (const float*)d_in[3];
    const float* b1    = (const float*)d_in[4];
    const float* W2    = (const float*)d_in[5];
    const float* b2    = (const float*)d_in[6];
    const float* W3    = (const float*)d_in[7];
    const float* b3    = (const float*)d_in[8];
    float*       out   = (float*)d_out;

    din15_kernel<<<BB / 8, 256, 0, stream>>>(query, hist, hlen, W1, b1, W2,
                                             b2, W3, b3, out);
}